// Round 9
// baseline (346.357 us; speedup 1.0000x reference)
//
#include <hip/hip_runtime.h>
#include <math.h>
#include <stdint.h>

// GlobalAttentionPool: score = segsum_edges(x[src].W_rel)[dst] + x.W_root (+b_rel,
// cancels in softmax); att = per-graph softmax; out = segsum(x*att).
//
// R2: scattered global atomics never coalesce (~18.6G/s) -> minimize COUNT.
// R8: LDS int fixed-point ds_add_u32. R9/R11: staged LDS->linear sort writes.
// R10 (FAILED): serial work in ONE wave. R12: 2-barrier scan + int4 loads.
// R13 (FALSIFIED): XCD-replicated cursors null.
// R14/R15 (MEASUREMENT): pad-spin attribution (~100MHz, additive): edge_sort
//     ~16us, pool ~20us, node_prep ~5, finalize ~1; residual ~70us = harness
//     re-poison fill (42.5us/256MiB in-window) + memset train + gaps.
// R16: fused bucket_accum+pool: 125 -> 118.5.
// R17 (FALSIFIED): float4+shfl pool fast path +2.6us.
// R18: Phase-A wave-split null. FETCH 16.3MB (poison evicts x from L3).
// R19 (FAILED): issue-early reg-staging spilled to scratch (WRITE 25.2MB).
// R20 (FALSIFIED): segment-merged output atomics (203K->63K) -> -0.9us only.
//     FOUR pool theories dead without ever measuring its phase split.
// R21 (ABLATION ROUND, pre-committed at R20): pad real bucket_pool (+49.5us)
//     + three padded SCRATCH-output variants after finalize:
//       bp<512, A+B>   -> tAB   (keepalive: e -> e2)
//       bp<512, B+C>   -> tBC   (A skipped, e=exp(r))
//       bp<1024, full> -> D1024 (occupancy A/B: 8 -> 16 waves/block;
//                               391 blocks = 1.5/CU, barrier drains leave
//                               single-block CUs empty)
//     dur_us expected ~340-360 (measurement overhead only, reverts next rd).
//     Decide: D1024 < D512-3 -> adopt; tAB >= 12 -> attack Phase A;
//     tBC >= 14 & D1024 null -> C = HBM-latency floor -> 2-bucket pipeline
//     or mega-fusion.

#define H 64
#define TILE 4096           // edges per sort tile
#define NTHR_S 1024
#define EPT (TILE / NTHR_S) // 4
#define BUCKET_SZ 256       // nodes per bucket
#define MAX_NB 400          // >= ceil(100000/256) = 391
#define NREP 8              // cursor replicas (== #XCDs)
#define SUBCAP 768          // slots per (bucket, replica); mean ~513
#define CAP (NREP * SUBCAP) // 6144 slots per bucket
#define PSCALE 16384.0f     // 2^14 fixed-point scale
#define INV_PSCALE 6.103515625e-05f
#define PAD_BP 5000ULL      // +49.5us visibility pad (calibrated R14/R15)

__device__ __forceinline__ void spin_pad(unsigned long long ticks)
{
    unsigned long long t0 = __builtin_amdgcn_s_memrealtime();
    while (__builtin_amdgcn_s_memrealtime() - t0 < ticks) { }
}

// K1: per-node dots p = x.W_rel, r = x.W_root (4 threads/node, float4 loads);
// zero num[]/z[]; init cursor[rep*nb + k] = k*CAP + rep*SUBCAP.
__global__ __launch_bounds__(256) void node_prep(
    const float4* __restrict__ x4, const float4* __restrict__ W_rel4,
    const float4* __restrict__ W_root4,
    float* __restrict__ p, float* __restrict__ r,
    float* __restrict__ num, float* __restrict__ z,
    unsigned int* __restrict__ cursor,
    int n_nodes, int num_elems, int n_graphs, int nb)
{
    int gid = (int)(blockIdx.x * blockDim.x + threadIdx.x);
    if (gid < num_elems) num[gid] = 0.0f;
    else if (gid < num_elems + n_graphs) z[gid - num_elems] = 0.0f;
    else if (gid < num_elems + n_graphs + nb * NREP) {
        int idx = gid - num_elems - n_graphs;    // == rep*nb + k
        int rep = idx / nb;
        int k   = idx - rep * nb;
        cursor[idx] = (unsigned int)(k * CAP + rep * SUBCAP);
    }

    int node = blockIdx.x * 64 + (threadIdx.x >> 2);
    int q    = threadIdx.x & 3;
    if (node >= n_nodes) return;

    float pv = 0.0f, rv = 0.0f;
    #pragma unroll
    for (int kk = 0; kk < 4; ++kk) {
        float4 v  = x4[node * 16 + kk * 4 + q];
        float4 wr = W_rel4[kk * 4 + q];
        float4 wo = W_root4[kk * 4 + q];
        pv += v.x * wr.x + v.y * wr.y + v.z * wr.z + v.w * wr.w;
        rv += v.x * wo.x + v.y * wo.y + v.z * wo.z + v.w * wo.w;
    }
    pv += __shfl_xor(pv, 1, 64); pv += __shfl_xor(pv, 2, 64);
    rv += __shfl_xor(rv, 1, 64); rv += __shfl_xor(rv, 2, 64);
    if (q == 0) { p[node] = pv; r[node] = rv; }
}

// K2: per-tile bucket partition with staged coalesced writes. 1024 threads.
// Payload = (round(p[src]*2^14) << 8) | (dst & 255).
__global__ __launch_bounds__(NTHR_S) void edge_sort(
    const int* __restrict__ src, const int* __restrict__ dst,
    const float* __restrict__ p,
    unsigned int* __restrict__ cursor, unsigned int* __restrict__ sorted_g,
    int n_edges, int nb)
{
    __shared__ unsigned int hist[MAX_NB];
    __shared__ unsigned int offs[MAX_NB];
    __shared__ unsigned int gbase[MAX_NB];
    __shared__ unsigned int wtot[8];
    __shared__ unsigned int svals[TILE];          // 16 KB payloads
    __shared__ unsigned short sbid[TILE];         // 8 KB bucket ids

    int b = blockIdx.x;
    int rep = b & (NREP - 1);                     // == XCD id (round-robin)
    int base = b * TILE;
    int tile_n = min(TILE, n_edges - base);
    int tid = threadIdx.x;

    if (tid < nb) hist[tid] = 0;
    __syncthreads();

    unsigned int dd[EPT]; int ss[EPT];
    float pv[EPT];
    unsigned int bk[EPT], pk[EPT], slot[EPT];

    int j0 = tid * EPT;                    // 4 consecutive edges per thread
    if (j0 + EPT <= tile_n) {
        int4 s4 = *(const int4*)(src + base + j0);
        int4 d4 = *(const int4*)(dst + base + j0);
        ss[0] = s4.x; ss[1] = s4.y; ss[2] = s4.z; ss[3] = s4.w;
        dd[0] = (unsigned int)d4.x; dd[1] = (unsigned int)d4.y;
        dd[2] = (unsigned int)d4.z; dd[3] = (unsigned int)d4.w;
    } else {
        #pragma unroll
        for (int u = 0; u < EPT; ++u) {
            int j = j0 + u;
            if (j < tile_n) { ss[u] = src[base + j];
                              dd[u] = (unsigned int)dst[base + j]; }
            else dd[u] = 0xFFFFFFFFu;
        }
    }
    #pragma unroll
    for (int u = 0; u < EPT; ++u)          // batched p gathers (ILP)
        if (dd[u] != 0xFFFFFFFFu) pv[u] = p[ss[u]];
    #pragma unroll
    for (int u = 0; u < EPT; ++u) {
        if (dd[u] != 0xFFFFFFFFu) {
            bk[u] = dd[u] >> 8;
            int q = (int)__float2int_rn(pv[u] * PSCALE);
            q = max(-8388607, min(8388607, q));          // 24-bit clamp
            pk[u] = ((unsigned int)q << 8) | (dd[u] & 255u);
            slot[u] = atomicAdd(&hist[bk[u]], 1u);
        }
    }
    __syncthreads();

    // ---- Pass B: 2-barrier scan ----
    int wv = tid >> 6, ln = tid & 63;
    unsigned int v = 0, xs = 0;
    if (wv < 7) {
        int bin = wv * 64 + ln;                    // 0..447 covers nb<=400
        v = (bin < nb) ? hist[bin] : 0;
        xs = v;                                     // inclusive shuffle scan
        #pragma unroll
        for (int off = 1; off < 64; off <<= 1) {
            unsigned int y = __shfl_up(xs, off, 64);
            if (ln >= off) xs += y;
        }
        if (ln == 63) wtot[wv] = xs;
    }
    __syncthreads();
    if (wv < 7) {
        int bin = wv * 64 + ln;
        unsigned int pre = 0;
        #pragma unroll
        for (int w2 = 0; w2 < 7; ++w2)
            pre += (w2 < wv) ? wtot[w2] : 0u;
        if (bin < nb) {
            offs[bin]  = pre + xs - v;             // exclusive prefix
            gbase[bin] = v ? atomicAdd(&cursor[rep * nb + bin], v) : 0u;
        }
    }
    __syncthreads();

    // ---- Pass C: LDS scatter into run order ----
    #pragma unroll
    for (int u = 0; u < EPT; ++u) {
        if (dd[u] != 0xFFFFFFFFu) {
            unsigned int pos = offs[bk[u]] + slot[u];
            svals[pos] = pk[u];
            sbid[pos]  = (unsigned short)bk[u];
        }
    }
    __syncthreads();

    // ---- Pass D: linear write (consecutive j -> consecutive global) ----
    for (int j = tid; j < tile_n; j += NTHR_S) {
        unsigned int bb = sbid[j];
        unsigned int gi = gbase[bb] + ((unsigned int)j - offs[bb]);
        unsigned int lim = bb * (unsigned int)CAP
                         + (unsigned int)(rep + 1) * SUBCAP;
        if (gi < lim)                               // sub-region overflow guard
            sorted_g[gi] = svals[j];
    }
}

// K3 templated (fused bucket_accum + pool), one block per 256-node bucket.
// NTHR in {512,1024} (8 or 16 waves). MODE: 0 = full, 1 = A+B only
// (keepalive e->e2), 2 = B+C only (A skipped; e=exp(r), junk-valid timing).
// Phase A: RPW waves per replica scan it with uint4 + ds_add_u32.
// Phase B: e_lds = exp(acc*s + r).
// Phase C1: each wave pools RW rows into first/last-graph register partials
//   (interior-graph fallback atomics); partials -> LDS.
// Phase C2: wave 0 merges the ordered segments -> one atomic per distinct
//   (graph,lane) per block.
// All variants end with a +49.5us visibility pad (R21 measurement).
template<int NTHR, int MODE>
__global__ __launch_bounds__(NTHR) void bucket_pool_t(
    const unsigned int* __restrict__ sorted_g,
    const unsigned int* __restrict__ cursor,
    const float* __restrict__ r,
    const float* __restrict__ x,
    const int* __restrict__ batch,
    float* __restrict__ num, float* __restrict__ z,
    float* __restrict__ e2,
    int n_nodes, int nb)
{
    constexpr int WAVES = NTHR / 64;
    constexpr int RPW   = WAVES / NREP;        // waves per replica (1 or 2)
    constexpr int RW    = BUCKET_SZ / WAVES;   // rows per wave in C (32 or 16)
    constexpr int NSEG  = 2 * WAVES;

    __shared__ int acc[BUCKET_SZ];
    __shared__ float e_lds[BUCKET_SZ];
    __shared__ int g_lds[BUCKET_SZ];
    __shared__ unsigned int cnts[NREP];
    __shared__ float pnum[NSEG][H];
    __shared__ float pz[NSEG];
    __shared__ int   sgid[NSEG];

    int k = blockIdx.x;
    int tid = threadIdx.x;
    int node0 = k * BUCKET_SZ;

    if (tid < BUCKET_SZ) acc[tid] = 0;
    else if (tid < 2 * BUCKET_SZ) {
        int t2 = tid - BUCKET_SZ;                 // 0..255
        int node = node0 + t2;
        g_lds[t2] = (node < n_nodes) ? batch[node] : -1;
    }
    if (tid < NREP) {
        unsigned int begr = (unsigned int)(k * CAP + tid * SUBCAP);
        cnts[tid] = min(cursor[tid * nb + k] - begr, (unsigned int)SUBCAP);
    }
    if (tid < NSEG) sgid[tid] = -1;
    __syncthreads();

    int wid = tid >> 6, lane = tid & 63;

    // ---- Phase A ----
    if (MODE != 2) {
        int rep_id = wid / RPW;
        int sub    = (wid % RPW) * 64 + lane;     // 0..RPW*64-1
        const int W = RPW * 64;
        unsigned int beg = (unsigned int)(k * CAP + rep_id * SUBCAP);
        unsigned int cnt = cnts[rep_id];
        unsigned int n4  = cnt & ~3u;
        for (unsigned int j = (unsigned int)sub * 4; j < n4;
             j += (unsigned int)W * 4) {
            uint4 v = *(const uint4*)(sorted_g + beg + j);
            atomicAdd(&acc[v.x & 255u], (int)v.x >> 8);
            atomicAdd(&acc[v.y & 255u], (int)v.y >> 8);
            atomicAdd(&acc[v.z & 255u], (int)v.z >> 8);
            atomicAdd(&acc[v.w & 255u], (int)v.w >> 8);
        }
        for (unsigned int j = n4 + (unsigned int)sub; j < cnt;
             j += (unsigned int)W) {
            unsigned int v = sorted_g[beg + j];
            atomicAdd(&acc[v & 255u], (int)v >> 8);
        }
    }
    __syncthreads();

    // ---- Phase B ----
    if (tid < BUCKET_SZ) {
        int node = node0 + tid;
        e_lds[tid] = (node < n_nodes)
                   ? __expf((float)acc[tid] * INV_PSCALE + r[node]) : 0.0f;
        if (MODE == 1 && node < n_nodes) e2[node] = e_lds[tid]; // keepalive
    }
    __syncthreads();

    if (MODE == 1) { spin_pad(PAD_BP); return; }

    // ---- Phase C1: per-wave window partials (x direct, coalesced) ----
    int l0 = wid * RW;
    int row0 = node0 + l0;
    int s0 = wid * 2;
    if (row0 < n_nodes) {
        int rend = min(row0 + RW, n_nodes);
        int gF = g_lds[l0];
        int gL = g_lds[rend - 1 - node0];
        float sA = 0.0f, sB = 0.0f, zA = 0.0f, zB = 0.0f;
        int nrows = rend - row0;
        #pragma unroll 8
        for (int u = 0; u < nrows; ++u) {
            int li = l0 + u;
            int g = g_lds[li];                    // wave-uniform
            float e = e_lds[li];
            float v = x[(size_t)(row0 + u) * H + lane] * e;
            if (g == gF)      { sA += v; zA += e; }
            else if (g == gL) { sB += v; zB += e; }
            else {                                // graph interior to window
                unsafeAtomicAdd(&num[g * H + lane], v);
                if (lane == 0) unsafeAtomicAdd(&z[g], e);
            }
        }
        pnum[s0][lane] = sA;
        if (lane == 0) { sgid[s0] = gF; pz[s0] = zA; }
        if (gL != gF) {
            pnum[s0 + 1][lane] = sB;
            if (lane == 0) { sgid[s0 + 1] = gL; pz[s0 + 1] = zB; }
        }
    }
    __syncthreads();

    // ---- Phase C2: wave 0 merges ordered segments -> per-graph atomics ----
    if (wid == 0) {
        float run = 0.0f, runz = 0.0f; int cur = -1;
        for (int s = 0; s < NSEG; ++s) {
            int id = sgid[s];                     // non-decreasing over s
            if (id < 0) continue;
            float v  = pnum[s][lane];
            float zv = pz[s];
            if (id != cur) {
                if (cur >= 0) {
                    unsafeAtomicAdd(&num[cur * H + lane], run);
                    if (lane == 0) unsafeAtomicAdd(&z[cur], runz);
                }
                cur = id; run = v; runz = zv;
            } else { run += v; runz += zv; }
        }
        if (cur >= 0) {
            unsafeAtomicAdd(&num[cur * H + lane], run);
            if (lane == 0) unsafeAtomicAdd(&z[cur], runz);
        }
    }
    spin_pad(PAD_BP);
}

// K4: out = num / z (plain stores; empty graphs -> 0).
__global__ __launch_bounds__(256) void finalize(
    const float* __restrict__ num, const float* __restrict__ z,
    float* __restrict__ out, int num_elems)
{
    int i = (int)(blockIdx.x * blockDim.x + threadIdx.x);
    if (i >= num_elems) return;
    float zz = z[i >> 6];
    out[i] = (zz != 0.0f) ? num[i] / zz : 0.0f;
}

extern "C" void kernel_launch(void* const* d_in, const int* in_sizes, int n_in,
                              void* d_out, int out_size, void* d_ws, size_t ws_size,
                              hipStream_t stream)
{
    const float* x      = (const float*)d_in[0];
    const int*   eidx   = (const int*)d_in[1];   // [2, E] int32
    const int*   batch  = (const int*)d_in[2];   // [N] int32, sorted
    const float* W_rel  = (const float*)d_in[3];
    // d_in[4] = b_rel: cancels in softmax
    const float* W_root = (const float*)d_in[5];
    float* out = (float*)d_out;

    const int n_nodes  = in_sizes[0] / H;          // 100000
    const int n_edges  = in_sizes[1] / 2;          // 1600000
    const int n_graphs = out_size / H;             // 512
    const int nb     = (n_nodes + BUCKET_SZ - 1) / BUCKET_SZ;   // 391
    const int ntiles = (n_edges + TILE - 1) / TILE;             // 391

    const int* src = eidx;
    const int* dst = eidx + n_edges;

    // workspace: p[N] r[N] z[G] num[G*H] cursor[nb*NREP] | sorted_g |
    //            scratch: num2[G*H] z2[G] e2[N]
    float* p     = (float*)d_ws;
    float* r     = p + n_nodes;
    float* z     = r + n_nodes;
    float* num   = z + n_graphs;
    unsigned int* cursor = (unsigned int*)(num + out_size);
    uintptr_t raw = (uintptr_t)(cursor + nb * NREP);
    unsigned int* sorted_g = (unsigned int*)((raw + 15) & ~(uintptr_t)15);
    float* num2 = (float*)(sorted_g + (size_t)nb * CAP);
    float* z2   = num2 + out_size;
    float* e2   = z2 + n_graphs;

    int np_blocks = (n_nodes + 63) / 64;   // 1563; also covers zero-init range
    node_prep<<<np_blocks, 256, 0, stream>>>(
        (const float4*)x, (const float4*)W_rel, (const float4*)W_root,
        p, r, num, z, cursor, n_nodes, out_size, n_graphs, nb);
    edge_sort<<<ntiles, NTHR_S, 0, stream>>>(src, dst, p, cursor, sorted_g,
                                             n_edges, nb);
    // real (padded for counter visibility)
    bucket_pool_t<512, 0><<<nb, 512, 0, stream>>>(
        sorted_g, cursor, r, x, batch, num, z, e2, n_nodes, nb);
    finalize<<<(out_size + 255) / 256, 256, 0, stream>>>(num, z, out, out_size);

    // ---- R21 ablation probes (scratch output, padded, after finalize) ----
    bucket_pool_t<512, 1><<<nb, 512, 0, stream>>>(      // A+B only
        sorted_g, cursor, r, x, batch, num2, z2, e2, n_nodes, nb);
    bucket_pool_t<512, 2><<<nb, 512, 0, stream>>>(      // B+C only
        sorted_g, cursor, r, x, batch, num2, z2, e2, n_nodes, nb);
    bucket_pool_t<1024, 0><<<nb, 1024, 0, stream>>>(    // 16-wave full A/B
        sorted_g, cursor, r, x, batch, num2, z2, e2, n_nodes, nb);
}

// Round 10
// 109.478 us; speedup vs baseline: 3.1637x; 3.1637x over previous
//
#include <hip/hip_runtime.h>
#include <math.h>
#include <stdint.h>

// GlobalAttentionPool: score = segsum_edges(x[src].W_rel)[dst] + x.W_root (+b_rel,
// cancels in softmax); att = per-graph softmax; out = segsum(x*att).
//
// R2: scattered global atomics never coalesce (~18.6G/s) -> minimize COUNT.
// R8: LDS int fixed-point ds_add_u32. R9/R11: staged LDS->linear sort writes.
// R10 (FAILED): serial work in ONE wave. R12: 2-barrier scan + int4 loads.
// R13 (FALSIFIED): XCD-replicated cursors null.
// R14/R15 (MEASUREMENT): pad-spin attribution (~100MHz, additive): edge_sort
//     ~16us, pool ~20us, node_prep ~5, finalize ~1; residual ~70us = harness
//     re-poison fill (42.5us/256MiB in-window) + memset train + gaps.
// R16: fused bucket_accum+pool: 125 -> 118.5.
// R17 (FAILED): float4+shfl pool fast path +2.6us (mechanism now understood,
//     see R21). R18: Phase-A wave-split null; FETCH 16.3MB (x evicted by
//     poison). R19 (FAILED): cross-barrier reg-staging spilled to scratch.
// R20 (NULL): segment-merged output atomics 203K->63K -> -0.9us.
// R21 (ABLATION): full == B+C == 18.5us true -> Phase C is 100% of
//     bucket_pool; A+B serial cost ~0; 16-wave variant not clearly better.
//     Little's law on C's counters (16.3MB @ 0.9TB/s, ~430ns latency) ->
//     only ~9 lines/CU in flight == <1 outstanding load per wave: the
//     per-iteration LDS(e,g) + global(x) interleave makes the compiler's
//     merged s_waitcnt (lgkmcnt(0) drains vmcnt too) serialize x loads.
//     Explains R17's regression and R18/R20 nulls.
// R22 (this round): de-interleave phase C1: batch all 32 x loads into
//     registers (full unroll, compile-time idx, no barrier crossing -> no
//     R19 spill), THEN read e/g from LDS and accumulate (branches+fallback
//     atomics after the loads). 32 loads in flight/wave instead of ~1.
//     Predict bucket_pool 18.5 -> ~8-10, dur 117.6 -> ~107-111.
//     Pre-commit: dur >= 115 -> R23 mega-fusion for gaps, then floor.

#define H 64
#define TILE 4096           // edges per sort tile
#define NTHR_S 1024
#define EPT (TILE / NTHR_S) // 4
#define BUCKET_SZ 256       // nodes per bucket
#define MAX_NB 400          // >= ceil(100000/256) = 391
#define NREP 8              // cursor replicas (== #XCDs)
#define SUBCAP 768          // slots per (bucket, replica); mean ~513
#define CAP (NREP * SUBCAP) // 6144 slots per bucket
#define PSCALE 16384.0f     // 2^14 fixed-point scale
#define INV_PSCALE 6.103515625e-05f

// K1: per-node dots p = x.W_rel, r = x.W_root (4 threads/node, float4 loads);
// zero num[]/z[]; init cursor[rep*nb + k] = k*CAP + rep*SUBCAP.
__global__ __launch_bounds__(256) void node_prep(
    const float4* __restrict__ x4, const float4* __restrict__ W_rel4,
    const float4* __restrict__ W_root4,
    float* __restrict__ p, float* __restrict__ r,
    float* __restrict__ num, float* __restrict__ z,
    unsigned int* __restrict__ cursor,
    int n_nodes, int num_elems, int n_graphs, int nb)
{
    int gid = (int)(blockIdx.x * blockDim.x + threadIdx.x);
    if (gid < num_elems) num[gid] = 0.0f;
    else if (gid < num_elems + n_graphs) z[gid - num_elems] = 0.0f;
    else if (gid < num_elems + n_graphs + nb * NREP) {
        int idx = gid - num_elems - n_graphs;    // == rep*nb + k
        int rep = idx / nb;
        int k   = idx - rep * nb;
        cursor[idx] = (unsigned int)(k * CAP + rep * SUBCAP);
    }

    int node = blockIdx.x * 64 + (threadIdx.x >> 2);
    int q    = threadIdx.x & 3;
    if (node >= n_nodes) return;

    float pv = 0.0f, rv = 0.0f;
    #pragma unroll
    for (int kk = 0; kk < 4; ++kk) {
        float4 v  = x4[node * 16 + kk * 4 + q];
        float4 wr = W_rel4[kk * 4 + q];
        float4 wo = W_root4[kk * 4 + q];
        pv += v.x * wr.x + v.y * wr.y + v.z * wr.z + v.w * wr.w;
        rv += v.x * wo.x + v.y * wo.y + v.z * wo.z + v.w * wo.w;
    }
    pv += __shfl_xor(pv, 1, 64); pv += __shfl_xor(pv, 2, 64);
    rv += __shfl_xor(rv, 1, 64); rv += __shfl_xor(rv, 2, 64);
    if (q == 0) { p[node] = pv; r[node] = rv; }
}

// K2: per-tile bucket partition with staged coalesced writes. 1024 threads.
// Payload = (round(p[src]*2^14) << 8) | (dst & 255).
__global__ __launch_bounds__(NTHR_S) void edge_sort(
    const int* __restrict__ src, const int* __restrict__ dst,
    const float* __restrict__ p,
    unsigned int* __restrict__ cursor, unsigned int* __restrict__ sorted_g,
    int n_edges, int nb)
{
    __shared__ unsigned int hist[MAX_NB];
    __shared__ unsigned int offs[MAX_NB];
    __shared__ unsigned int gbase[MAX_NB];
    __shared__ unsigned int wtot[8];
    __shared__ unsigned int svals[TILE];          // 16 KB payloads
    __shared__ unsigned short sbid[TILE];         // 8 KB bucket ids

    int b = blockIdx.x;
    int rep = b & (NREP - 1);                     // == XCD id (round-robin)
    int base = b * TILE;
    int tile_n = min(TILE, n_edges - base);
    int tid = threadIdx.x;

    if (tid < nb) hist[tid] = 0;
    __syncthreads();

    unsigned int dd[EPT]; int ss[EPT];
    float pv[EPT];
    unsigned int bk[EPT], pk[EPT], slot[EPT];

    int j0 = tid * EPT;                    // 4 consecutive edges per thread
    if (j0 + EPT <= tile_n) {
        int4 s4 = *(const int4*)(src + base + j0);
        int4 d4 = *(const int4*)(dst + base + j0);
        ss[0] = s4.x; ss[1] = s4.y; ss[2] = s4.z; ss[3] = s4.w;
        dd[0] = (unsigned int)d4.x; dd[1] = (unsigned int)d4.y;
        dd[2] = (unsigned int)d4.z; dd[3] = (unsigned int)d4.w;
    } else {
        #pragma unroll
        for (int u = 0; u < EPT; ++u) {
            int j = j0 + u;
            if (j < tile_n) { ss[u] = src[base + j];
                              dd[u] = (unsigned int)dst[base + j]; }
            else dd[u] = 0xFFFFFFFFu;
        }
    }
    #pragma unroll
    for (int u = 0; u < EPT; ++u)          // batched p gathers (ILP)
        if (dd[u] != 0xFFFFFFFFu) pv[u] = p[ss[u]];
    #pragma unroll
    for (int u = 0; u < EPT; ++u) {
        if (dd[u] != 0xFFFFFFFFu) {
            bk[u] = dd[u] >> 8;
            int q = (int)__float2int_rn(pv[u] * PSCALE);
            q = max(-8388607, min(8388607, q));          // 24-bit clamp
            pk[u] = ((unsigned int)q << 8) | (dd[u] & 255u);
            slot[u] = atomicAdd(&hist[bk[u]], 1u);
        }
    }
    __syncthreads();

    // ---- Pass B: 2-barrier scan ----
    int wv = tid >> 6, ln = tid & 63;
    unsigned int v = 0, xs = 0;
    if (wv < 7) {
        int bin = wv * 64 + ln;                    // 0..447 covers nb<=400
        v = (bin < nb) ? hist[bin] : 0;
        xs = v;                                     // inclusive shuffle scan
        #pragma unroll
        for (int off = 1; off < 64; off <<= 1) {
            unsigned int y = __shfl_up(xs, off, 64);
            if (ln >= off) xs += y;
        }
        if (ln == 63) wtot[wv] = xs;
    }
    __syncthreads();
    if (wv < 7) {
        int bin = wv * 64 + ln;
        unsigned int pre = 0;
        #pragma unroll
        for (int w2 = 0; w2 < 7; ++w2)
            pre += (w2 < wv) ? wtot[w2] : 0u;
        if (bin < nb) {
            offs[bin]  = pre + xs - v;             // exclusive prefix
            gbase[bin] = v ? atomicAdd(&cursor[rep * nb + bin], v) : 0u;
        }
    }
    __syncthreads();

    // ---- Pass C: LDS scatter into run order ----
    #pragma unroll
    for (int u = 0; u < EPT; ++u) {
        if (dd[u] != 0xFFFFFFFFu) {
            unsigned int pos = offs[bk[u]] + slot[u];
            svals[pos] = pk[u];
            sbid[pos]  = (unsigned short)bk[u];
        }
    }
    __syncthreads();

    // ---- Pass D: linear write (consecutive j -> consecutive global) ----
    for (int j = tid; j < tile_n; j += NTHR_S) {
        unsigned int bb = sbid[j];
        unsigned int gi = gbase[bb] + ((unsigned int)j - offs[bb]);
        unsigned int lim = bb * (unsigned int)CAP
                         + (unsigned int)(rep + 1) * SUBCAP;
        if (gi < lim)                               // sub-region overflow guard
            sorted_g[gi] = svals[j];
    }
}

// K3 (fused bucket_accum + pool), one 512-thread block per 256-node bucket.
//   Phase A: wave w accumulates replica sub-region w (uint4 + ds_add_u32).
//   Phase B: e_lds = exp(acc*s + r) in LDS.
//   Phase C1 (R22): BATCHED -- 32 pure global x loads into registers first
//     (full unroll, no LDS ops between them -> all 32 in flight), THEN LDS
//     e/g reads + segment accumulation (branches/fallback atomics here).
//   Phase C2: wave 0 merges ordered segments -> one atomic per distinct
//     (graph, lane) per block.
__global__ __launch_bounds__(512) void bucket_pool(
    const unsigned int* __restrict__ sorted_g,
    const unsigned int* __restrict__ cursor,
    const float* __restrict__ r,
    const float* __restrict__ x,
    const int* __restrict__ batch,
    float* __restrict__ num, float* __restrict__ z,
    int n_nodes, int nb)
{
    __shared__ int acc[BUCKET_SZ];
    __shared__ float e_lds[BUCKET_SZ];
    __shared__ int g_lds[BUCKET_SZ];
    __shared__ unsigned int cnts[NREP];
    __shared__ float pnum[2 * NREP][H];           // 4 KB segment partials
    __shared__ float pz[2 * NREP];
    __shared__ int   sgid[2 * NREP];

    int k = blockIdx.x;
    int tid = threadIdx.x;
    int node0 = k * BUCKET_SZ;

    if (tid < BUCKET_SZ) acc[tid] = 0;
    else {
        int t2 = tid - BUCKET_SZ;                 // 0..255
        int node = node0 + t2;
        g_lds[t2] = (node < n_nodes) ? batch[node] : -1;
    }
    if (tid < NREP) {
        unsigned int begr = (unsigned int)(k * CAP + tid * SUBCAP);
        cnts[tid] = min(cursor[tid * nb + k] - begr, (unsigned int)SUBCAP);
    }
    if (tid < 2 * NREP) sgid[tid] = -1;
    __syncthreads();

    // ---- Phase A: wave w accumulates replica w ----
    {
        int wv = tid >> 6, ln = tid & 63;         // wv == replica id
        unsigned int beg = (unsigned int)(k * CAP + wv * SUBCAP);
        unsigned int cnt = cnts[wv];
        unsigned int n4  = cnt & ~3u;
        for (unsigned int j = ln * 4; j < n4; j += 256) {
            uint4 v = *(const uint4*)(sorted_g + beg + j);
            atomicAdd(&acc[v.x & 255u], (int)v.x >> 8);
            atomicAdd(&acc[v.y & 255u], (int)v.y >> 8);
            atomicAdd(&acc[v.z & 255u], (int)v.z >> 8);
            atomicAdd(&acc[v.w & 255u], (int)v.w >> 8);
        }
        for (unsigned int j = n4 + ln; j < cnt; j += 64) {
            unsigned int v = sorted_g[beg + j];
            atomicAdd(&acc[v & 255u], (int)v >> 8);
        }
    }
    __syncthreads();

    // ---- Phase B: e = exp(score) in LDS ----
    if (tid < BUCKET_SZ) {
        int node = node0 + tid;
        e_lds[tid] = (node < n_nodes)
                   ? __expf((float)acc[tid] * INV_PSCALE + r[node]) : 0.0f;
    }
    __syncthreads();

    // ---- Phase C1: batched loads, then accumulate ----
    int wid = tid >> 6, lane = tid & 63;
    int l0 = wid * 32;
    int row0 = node0 + l0;
    int s0 = wid * 2;
    if (row0 < n_nodes) {
        int rend = min(row0 + 32, n_nodes);
        int gF = g_lds[l0];
        int gL = g_lds[rend - 1 - node0];
        float sA = 0.0f, sB = 0.0f, zA = 0.0f, zB = 0.0f;

        if (rend - row0 == 32) {
            // batched path: 32 pure global loads, all in flight
            float xv[32];
            const float* xp = x + (size_t)row0 * H + lane;
            #pragma unroll
            for (int u = 0; u < 32; ++u)
                xv[u] = xp[u * H];
            // accumulate (LDS reads + branches AFTER all loads issued)
            #pragma unroll
            for (int u = 0; u < 32; ++u) {
                int li = l0 + u;
                int g = g_lds[li];                // wave-uniform
                float e = e_lds[li];
                float v = xv[u] * e;
                if (g == gF)      { sA += v; zA += e; }
                else if (g == gL) { sB += v; zB += e; }
                else {                            // graph interior to window
                    unsafeAtomicAdd(&num[g * H + lane], v);
                    if (lane == 0) unsafeAtomicAdd(&z[g], e);
                }
            }
        } else {
            // generic tail path (not hit at N=100000: windows are full)
            for (int i = row0; i < rend; ++i) {
                int li = i - node0;
                int g = g_lds[li];
                float e = e_lds[li];
                float v = x[(size_t)i * H + lane] * e;
                if (g == gF)      { sA += v; zA += e; }
                else if (g == gL) { sB += v; zB += e; }
                else {
                    unsafeAtomicAdd(&num[g * H + lane], v);
                    if (lane == 0) unsafeAtomicAdd(&z[g], e);
                }
            }
        }
        pnum[s0][lane] = sA;
        if (lane == 0) { sgid[s0] = gF; pz[s0] = zA; }
        if (gL != gF) {
            pnum[s0 + 1][lane] = sB;
            if (lane == 0) { sgid[s0 + 1] = gL; pz[s0 + 1] = zB; }
        }
    }
    __syncthreads();

    // ---- Phase C2: wave 0 merges ordered segments -> per-graph atomics ----
    if (wid == 0) {
        float run = 0.0f, runz = 0.0f; int cur = -1;
        for (int s = 0; s < 2 * NREP; ++s) {
            int id = sgid[s];                     // non-decreasing over s
            if (id < 0) continue;
            float v  = pnum[s][lane];
            float zv = pz[s];
            if (id != cur) {
                if (cur >= 0) {
                    unsafeAtomicAdd(&num[cur * H + lane], run);
                    if (lane == 0) unsafeAtomicAdd(&z[cur], runz);
                }
                cur = id; run = v; runz = zv;
            } else { run += v; runz += zv; }
        }
        if (cur >= 0) {
            unsafeAtomicAdd(&num[cur * H + lane], run);
            if (lane == 0) unsafeAtomicAdd(&z[cur], runz);
        }
    }
}

// K4: out = num / z (plain stores; empty graphs -> 0).
__global__ __launch_bounds__(256) void finalize(
    const float* __restrict__ num, const float* __restrict__ z,
    float* __restrict__ out, int num_elems)
{
    int i = (int)(blockIdx.x * blockDim.x + threadIdx.x);
    if (i >= num_elems) return;
    float zz = z[i >> 6];
    out[i] = (zz != 0.0f) ? num[i] / zz : 0.0f;
}

extern "C" void kernel_launch(void* const* d_in, const int* in_sizes, int n_in,
                              void* d_out, int out_size, void* d_ws, size_t ws_size,
                              hipStream_t stream)
{
    const float* x      = (const float*)d_in[0];
    const int*   eidx   = (const int*)d_in[1];   // [2, E] int32
    const int*   batch  = (const int*)d_in[2];   // [N] int32, sorted
    const float* W_rel  = (const float*)d_in[3];
    // d_in[4] = b_rel: cancels in softmax
    const float* W_root = (const float*)d_in[5];
    float* out = (float*)d_out;

    const int n_nodes  = in_sizes[0] / H;          // 100000
    const int n_edges  = in_sizes[1] / 2;          // 1600000
    const int n_graphs = out_size / H;             // 512
    const int nb     = (n_nodes + BUCKET_SZ - 1) / BUCKET_SZ;   // 391
    const int ntiles = (n_edges + TILE - 1) / TILE;             // 391

    const int* src = eidx;
    const int* dst = eidx + n_edges;

    // workspace: p[N] r[N] z[G] num[G*H] cursor[nb*NREP] | sorted_g (16B align)
    float* p     = (float*)d_ws;
    float* r     = p + n_nodes;
    float* z     = r + n_nodes;
    float* num   = z + n_graphs;
    unsigned int* cursor = (unsigned int*)(num + out_size);
    uintptr_t raw = (uintptr_t)(cursor + nb * NREP);
    unsigned int* sorted_g = (unsigned int*)((raw + 15) & ~(uintptr_t)15);

    int np_blocks = (n_nodes + 63) / 64;   // 1563; also covers zero-init range
    node_prep<<<np_blocks, 256, 0, stream>>>(
        (const float4*)x, (const float4*)W_rel, (const float4*)W_root,
        p, r, num, z, cursor, n_nodes, out_size, n_graphs, nb);
    edge_sort<<<ntiles, NTHR_S, 0, stream>>>(src, dst, p, cursor, sorted_g,
                                             n_edges, nb);
    bucket_pool<<<nb, 512, 0, stream>>>(sorted_g, cursor, r, x, batch,
                                        num, z, n_nodes, nb);
    finalize<<<(out_size + 255) / 256, 256, 0, stream>>>(num, z, out, out_size);
}